// Round 1
// baseline (341.310 us; speedup 1.0000x reference)
//
#include <hip/hip_runtime.h>
#include <cstdint>
#include <cstddef>

#define FDIM 1024   // feature dim F
#define DDIM 128    // fc out dim D
#define NGRAPH 64   // num graphs B
#define FCH 8       // feature chunks (XCD-local gather)
#define QN 4        // node quarters per graph
#define FILLB 320   // fill-block range in k_fill_gemm (mult of 8)

// GEMM tile (R7): 256x128, BK=64 -> 64 MFMA per barrier-pair per wave
#define BM 256
#define BN 128
#define BK 64

#define AS1 __attribute__((address_space(1)))
#define AS3 __attribute__((address_space(3)))

typedef float f32x4 __attribute__((ext_vector_type(4)));
typedef short s16x8 __attribute__((ext_vector_type(8)));
typedef unsigned short u16x8 __attribute__((ext_vector_type(8)));

__device__ __forceinline__ unsigned short f2bf(float f) {
  unsigned int x = __float_as_uint(f);
  unsigned int r = (x + 0x7fffu + ((x >> 16) & 1u)) >> 16;  // RNE
  return (unsigned short)r;
}
__device__ __forceinline__ float bflo(unsigned int v) {
  return __uint_as_float(v << 16);
}
__device__ __forceinline__ float bfhi(unsigned int v) {
  return __uint_as_float(v & 0xffff0000u);
}

__device__ __forceinline__ int lower_bound(const int* a, int n, int v) {
  int lo = 0, hi = n;
  while (lo < hi) {
    int mid = (lo + hi) >> 1;
    if (a[mid] < v) lo = mid + 1; else hi = mid;
  }
  return lo;
}

// ---------------------------------------------------------------------------
// prep+cast (merged, grid.y = branch):
//   x in [0, gE)            : in-degree atomics (deg pre-zeroed by memset;
//                             self-loop +1 is applied inside k_scan)
//   x in [gE, gE+nxb)       : x fp32 -> bf16 cast, 32B in / 16B out per thread
//   x in [gE+nxb, +256)     : W cast+transpose (64x64 LDS tiles)
// ---------------------------------------------------------------------------
__global__ __launch_bounds__(256) void k_prep_cast(const int* __restrict__ ei1,
                                                   const int* __restrict__ ei2,
                                                   int* deg1, int* deg2,
                                                   const float4* __restrict__ x1,
                                                   const float4* __restrict__ x2,
                                                   const float* __restrict__ W1,
                                                   const float* __restrict__ W2,
                                                   u16x8* xb1, u16x8* xb2,
                                                   unsigned short* Wt1, unsigned short* Wt2,
                                                   int E, int n8, int gE, int nxb) {
  __shared__ unsigned short tile[64][65];
  int br = blockIdx.y;
  int x = blockIdx.x, t = threadIdx.x;
  if (x < gE) {
    const int* ei = br ? ei2 : ei1;
    int* deg = br ? deg2 : deg1;
    int i = x * 256 + t;
    if (i < E) atomicAdd(&deg[ei[E + i]], 1);
  } else if (x < gE + nxb) {
    const float4* xx = br ? x2 : x1;
    u16x8* xb = br ? xb2 : xb1;
    int i = (x - gE) * 256 + t;
    if (i < n8) {
      float4 v0 = xx[2 * i];
      float4 v1 = xx[2 * i + 1];
      u16x8 o;
      o[0] = f2bf(v0.x); o[1] = f2bf(v0.y); o[2] = f2bf(v0.z); o[3] = f2bf(v0.w);
      o[4] = f2bf(v1.x); o[5] = f2bf(v1.y); o[6] = f2bf(v1.z); o[7] = f2bf(v1.w);
      xb[i] = o;
    }
  } else {
    const float* W = br ? W2 : W1;
    unsigned short* Wt = br ? Wt2 : Wt1;
    int tid16 = x - gE - nxb;        // 0..255
    int kb = tid16 >> 4, nb = tid16 & 15;
    int tn = t & 63, tg = t >> 6;
    #pragma unroll
    for (int r = 0; r < 16; ++r) {
      int kk = tg * 16 + r;
      tile[kk][tn] = f2bf(W[(size_t)(kb * 64 + kk) * FDIM + nb * 64 + tn]);
    }
    __syncthreads();
    #pragma unroll
    for (int r = 0; r < 16; ++r) {
      int nn = tg * 16 + r;
      Wt[(size_t)(nb * 64 + nn) * FDIM + kb * 64 + tn] = tile[tn][nn];
    }
  }
}

// ---------------------------------------------------------------------------
// scan (merged): blockIdx.x = branch (0/1); block 2 = cnt/gstart binary search.
// deg holds in-degree only; self-loop +1 applied here (replaces k_init).
// ---------------------------------------------------------------------------
#define SCAN_T 1024
#define SCAN_PER 16
__global__ __launch_bounds__(SCAN_T) void k_scan(const int* __restrict__ deg1,
                                                 const int* __restrict__ deg2,
                                                 int* off1, int* off2,
                                                 int* cur1, int* cur2,
                                                 float* dinv1, float* dinv2,
                                                 const int* __restrict__ batch1,
                                                 const int* __restrict__ batch2,
                                                 int* cnt1, int* gstart1,
                                                 int* cnt2, int* gstart2, int n) {
  if (blockIdx.x == 2) {
    int t = threadIdx.x;
    if (t < 128) {
      const int* batch = (t < NGRAPH) ? batch1 : batch2;
      int* cnt = (t < NGRAPH) ? cnt1 : cnt2;
      int* gstart = (t < NGRAPH) ? gstart1 : gstart2;
      int g = t & (NGRAPH - 1);
      int lo = lower_bound(batch, n, g);
      int hi = lower_bound(batch, n, g + 1);
      gstart[g] = lo;
      cnt[g] = hi - lo;
    }
    return;
  }
  const int* deg = blockIdx.x ? deg2 : deg1;
  int* off = blockIdx.x ? off2 : off1;
  int* cur = blockIdx.x ? cur2 : cur1;
  float* dinv = blockIdx.x ? dinv2 : dinv1;
  __shared__ int sums[SCAN_T];
  int t = threadIdx.x;
  int base = t * SCAN_PER;
  int local[SCAN_PER];
  int s = 0;
  #pragma unroll
  for (int i = 0; i < SCAN_PER; ++i) {
    int idx = base + i;
    int d = (idx < n) ? (deg[idx] + 1) : 0;   // +1 = self-loop
    local[i] = s;
    s += d;
    if (idx < n) dinv[idx] = rsqrtf((float)d);
  }
  sums[t] = s;
  __syncthreads();
  for (int o = 1; o < SCAN_T; o <<= 1) {
    int v = (t >= o) ? sums[t - o] : 0;
    __syncthreads();
    sums[t] += v;
    __syncthreads();
  }
  int basesum = (t > 0) ? sums[t - 1] : 0;
  #pragma unroll
  for (int i = 0; i < SCAN_PER; ++i) {
    int idx = base + i;
    if (idx < n) { int o = basesum + local[i]; off[idx] = o; cur[idx] = o; }
  }
  if (t == SCAN_T - 1) off[n] = sums[SCAN_T - 1];
}

// ---------------------------------------------------------------------------
// fill+gemm (merged, grid.y = branch):
//   x in [0, FILLB)  : CSR fill (latency-bound atomics)
//   x in [FILLB, +mt*8) : bf16 MFMA GEMM, 256x128 tile / BK=64 (R7), XCD swz.
// 64 MFMA per wave per barrier-pair (was 16) -> barrier-drain stall / 4.
// ---------------------------------------------------------------------------
__global__ __launch_bounds__(256, 2) void k_fill_gemm(const int* __restrict__ ei1,
                                                      const int* __restrict__ ei2,
                                                      int* cur1, int* cur2,
                                                      const float* __restrict__ dinv1,
                                                      const float* __restrict__ dinv2,
                                                      int* adjsrc1, int* adjsrc2,
                                                      float* adjw1, float* adjw2,
                                                      const unsigned short* __restrict__ A1,
                                                      const unsigned short* __restrict__ A2,
                                                      const unsigned short* __restrict__ B1,
                                                      const unsigned short* __restrict__ B2,
                                                      unsigned short* __restrict__ C1,
                                                      unsigned short* __restrict__ C2,
                                                      int E, int N, int M) {
  __shared__ unsigned short sm[24576];  // As [0,16384) 256x64 ; Bs [16384,24576) 128x64
  int br = blockIdx.y;
  if (blockIdx.x < FILLB) {
    const int* ei = br ? ei2 : ei1;
    int* cur = br ? cur2 : cur1;
    const float* dinv = br ? dinv2 : dinv1;
    int* adjsrc = br ? adjsrc2 : adjsrc1;
    float* adjw = br ? adjw2 : adjw1;
    int i = blockIdx.x * 256 + threadIdx.x;
    if (i < E) {
      int s = ei[i];
      int d = ei[E + i];
      int p = atomicAdd(&cur[d], 1);
      adjsrc[p] = s;
      adjw[p] = dinv[s] * dinv[d];
    }
    if (i < N) {
      int p = atomicAdd(&cur[i], 1);
      adjsrc[p] = i;
      adjw[p] = dinv[i] * dinv[i];
    }
    return;
  }
  // ---- GEMM path (R7 256x128 / BK=64 config) ----
  const unsigned short* A = br ? A2 : A1;
  const unsigned short* Bt = br ? B2 : B1;
  unsigned short* C = br ? C2 : C1;
  const int K = FDIM;
  int tid = threadIdx.x;
  int w = tid >> 6, lane = tid & 63;
  int wm = w >> 1, wn = w & 1;

  int bx = blockIdx.x - FILLB;                 // 0 .. mt*8-1
  int per_xcd = (gridDim.x - FILLB) >> 3;
  int l = (bx & 7) * per_xcd + (bx >> 3);
  int m0 = (l >> 3) * BM;                      // ntiles == 8
  int n0 = (l & 7) * BN;

  int seg_r = lane >> 3;    // row within wave's 8-row staging segment
  int seg_c = lane & 7;     // 16B column segment (8 bf16 features)

  f32x4 acc[8][4];
  #pragma unroll
  for (int i = 0; i < 8; ++i)
    #pragma unroll
    for (int j = 0; j < 4; ++j)
      acc[i][j] = (f32x4){0.f, 0.f, 0.f, 0.f};

  for (int k0 = 0; k0 < K; k0 += BK) {
    // A: 256 rows x 128B. 8 segments of 32 rows; wave w stages 8 rows/segment.
    #pragma unroll
    for (int c = 0; c < 8; ++c) {
      int ra = m0 + c * 32 + w * 8 + seg_r;
      if (ra > M - 1) ra = M - 1;
      const unsigned short* ga = A + (size_t)ra * K + k0 + seg_c * 8;
      __builtin_amdgcn_global_load_lds((const AS1 unsigned int*)ga,
                                       (AS3 unsigned int*)&sm[c * 2048 + w * 512], 16, 0, 0);
    }
    // B: 128 rows x 128B. 4 segments of 32 rows.
    #pragma unroll
    for (int c = 0; c < 4; ++c) {
      int rb = n0 + c * 32 + w * 8 + seg_r;
      const unsigned short* gb = Bt + (size_t)rb * K + k0 + seg_c * 8;
      __builtin_amdgcn_global_load_lds((const AS1 unsigned int*)gb,
                                       (AS3 unsigned int*)&sm[16384 + c * 2048 + w * 512], 16, 0, 0);
    }
    __syncthreads();   // compiler drains vmcnt before s_barrier
    #pragma unroll
    for (int kk = 0; kk < 2; ++kk) {
      s16x8 af[8], bfr[4];
      #pragma unroll
      for (int i = 0; i < 8; ++i) {
        int rowa = wm * 128 + i * 16 + (lane & 15);
        af[i] = *(const s16x8*)&sm[rowa * 64 + kk * 32 + (lane >> 4) * 8];
      }
      #pragma unroll
      for (int j = 0; j < 4; ++j) {
        int rowb = wn * 64 + j * 16 + (lane & 15);
        bfr[j] = *(const s16x8*)&sm[16384 + rowb * 64 + kk * 32 + (lane >> 4) * 8];
      }
      #pragma unroll
      for (int i = 0; i < 8; ++i)
        #pragma unroll
        for (int j = 0; j < 4; ++j)
          acc[i][j] = __builtin_amdgcn_mfma_f32_16x16x32_bf16(af[i], bfr[j], acc[i][j], 0, 0, 0);
    }
    __syncthreads();
  }

  #pragma unroll
  for (int i = 0; i < 8; ++i) {
    int row_base = m0 + wm * 128 + i * 16 + (lane >> 4) * 4;
    #pragma unroll
    for (int j = 0; j < 4; ++j) {
      int col = n0 + wn * 64 + j * 16 + (lane & 15);
      #pragma unroll
      for (int r = 0; r < 4; ++r) {
        int row = row_base + r;
        if (row < M) C[(size_t)row * FDIM + col] = f2bf(acc[i][j][r]);
      }
    }
  }
}

// ---------------------------------------------------------------------------
// aggpool v4 (XCD-local, atomic-free): each (g,chunk,q) block writes its
// partial to pool4[q][g][f] with plain stores; fc sums partials.
// chunk == blockIdx.x & 7 == XCD id -> per-XCD gather set ~2.6MB (L2-resident)
// ---------------------------------------------------------------------------
__global__ __launch_bounds__(256) void k_aggpool(const unsigned short* __restrict__ h1,
                                                 const unsigned short* __restrict__ h2,
                                                 const int* __restrict__ off1,
                                                 const int* __restrict__ off2,
                                                 const int* __restrict__ adjsrc1,
                                                 const int* __restrict__ adjsrc2,
                                                 const float* __restrict__ adjw1,
                                                 const float* __restrict__ adjw2,
                                                 const float* __restrict__ bias1,
                                                 const float* __restrict__ bias2,
                                                 const int* __restrict__ cnt1,
                                                 const int* __restrict__ cnt2,
                                                 const int* __restrict__ gstart1,
                                                 const int* __restrict__ gstart2,
                                                 float* pool4_1, float* pool4_2) {
  int br = blockIdx.y;
  const unsigned short* h = br ? h2 : h1;
  const int* off = br ? off2 : off1;
  const int* adjsrc = br ? adjsrc2 : adjsrc1;
  const float* adjw = br ? adjw2 : adjw1;
  const float* bias = br ? bias2 : bias1;
  const int* cnt = br ? cnt2 : cnt1;
  const int* gstart = br ? gstart2 : gstart1;
  float* pool4 = br ? pool4_2 : pool4_1;

  int x = blockIdx.x;
  int chunk = x & (FCH - 1);
  int r = x >> 3;
  int g = r & (NGRAPH - 1);
  int q = r >> 6;

  int t = threadIdx.x;
  int grp = t >> 6, lane = t & 63;

  int n = cnt[g];
  int start = gstart[g];
  int per = (n + QN - 1) / QN;
  int v0 = start + q * per;
  int v1 = min(start + n, v0 + per);

  int colbase = chunk * 128 + lane * 2;
  const unsigned short* hc = h + colbase;
  float2 b2 = *(const float2*)(bias + colbase);
  float s0 = 0.f, s1 = 0.f;

  for (int v = v0 + grp; v < v1; v += 4) {
    int pb = off[v], pe = off[v + 1];
    float a0 = 0.f, a1 = 0.f;
    for (int pbb = pb; pbb < pe; pbb += 64) {
      int m = min(64, pe - pbb);
      int lp = pbb + ((lane < m) ? lane : (m - 1));
      int vs = adjsrc[lp];
      float vw = adjw[lp];
      int j = 0;
      for (; j + 4 <= m; j += 4) {
        int i0 = __shfl(vs, j),     i1 = __shfl(vs, j + 1);
        int i2 = __shfl(vs, j + 2), i3 = __shfl(vs, j + 3);
        float w0 = __shfl(vw, j),     w1 = __shfl(vw, j + 1);
        float w2 = __shfl(vw, j + 2), w3 = __shfl(vw, j + 3);
        unsigned int h0 = *(const unsigned int*)(hc + ((size_t)i0 << 10));
        unsigned int hv1 = *(const unsigned int*)(hc + ((size_t)i1 << 10));
        unsigned int hv2 = *(const unsigned int*)(hc + ((size_t)i2 << 10));
        unsigned int hv3 = *(const unsigned int*)(hc + ((size_t)i3 << 10));
        a0 += w0 * bflo(h0);  a1 += w0 * bfhi(h0);
        a0 += w1 * bflo(hv1); a1 += w1 * bfhi(hv1);
        a0 += w2 * bflo(hv2); a1 += w2 * bfhi(hv2);
        a0 += w3 * bflo(hv3); a1 += w3 * bfhi(hv3);
      }
      for (; j < m; ++j) {
        int i0 = __shfl(vs, j);
        float w0 = __shfl(vw, j);
        unsigned int h0 = *(const unsigned int*)(hc + ((size_t)i0 << 10));
        a0 += w0 * bflo(h0);
        a1 += w0 * bfhi(h0);
      }
    }
    a0 += b2.x; a1 += b2.y;
    s0 += (a0 >= 0.f) ? a0 : 0.01f * a0;
    s1 += (a1 >= 0.f) ? a1 : 0.01f * a1;
  }

  __shared__ float sm[4][128];
  sm[grp][lane * 2] = s0;
  sm[grp][lane * 2 + 1] = s1;
  __syncthreads();
  if (t < 128) {
    float sum = sm[0][t] + sm[1][t] + sm[2][t] + sm[3][t];
    float ic = 1.0f / fmaxf((float)n, 1.0f);
    pool4[((size_t)(q * NGRAPH + g)) * FDIM + chunk * 128 + t] = sum * ic;
  }
}

// ---------------------------------------------------------------------------
// fc+final (merged): one block per graph, 256 threads.
// t<128 -> branch1 fc row, t>=128 -> branch2; then dot with final_W + reduce.
// ---------------------------------------------------------------------------
__global__ __launch_bounds__(256) void k_fc_final(const float* __restrict__ pool4_1,
                                                  const float* __restrict__ pool4_2,
                                                  const float* __restrict__ W1,
                                                  const float* __restrict__ W2,
                                                  const float* __restrict__ b1,
                                                  const float* __restrict__ b2,
                                                  const float* __restrict__ fW,
                                                  const float* __restrict__ fb,
                                                  float* __restrict__ out) {
  int g = blockIdx.x;
  int t = threadIdx.x;
  int half = t >> 7;
  int j = t & 127;
  const float* pool4 = half ? pool4_2 : pool4_1;
  const float* W = half ? W2 : W1;
  const float* b = half ? b2 : b1;
  __shared__ float xs[2][FDIM];
  for (int k = j; k < FDIM; k += DDIM) {
    float v = 0.f;
    #pragma unroll
    for (int q = 0; q < QN; ++q)
      v += pool4[((size_t)(q * NGRAPH + g)) * FDIM + k];
    xs[half][k] = v;
  }
  __syncthreads();
  float acc = b[j];
  for (int k = 0; k < FDIM; ++k) acc += xs[half][k] * W[(size_t)k * DDIM + j];
  acc = (acc >= 0.f) ? acc : 0.01f * acc;
  float c = acc * fW[half * DDIM + j];
  #pragma unroll
  for (int o = 32; o > 0; o >>= 1) c += __shfl_down(c, o);
  __shared__ float ws[4];
  if ((t & 63) == 0) ws[t >> 6] = c;
  __syncthreads();
  if (t == 0) out[g] = ws[0] + ws[1] + ws[2] + ws[3] + fb[0];
}

// ---------------------------------------------------------------------------
extern "C" void kernel_launch(void* const* d_in, const int* in_sizes, int n_in,
                              void* d_out, int out_size, void* d_ws, size_t ws_size,
                              hipStream_t stream) {
  const float* x1 = (const float*)d_in[0];
  const int* ei1 = (const int*)d_in[1];
  const int* batch1 = (const int*)d_in[2];
  const float* x2 = (const float*)d_in[3];
  const int* ei2 = (const int*)d_in[4];
  const int* batch2 = (const int*)d_in[5];
  const float* conv1_W = (const float*)d_in[10];
  const float* conv1_b = (const float*)d_in[11];
  const float* fc1_W = (const float*)d_in[12];
  const float* fc1_b = (const float*)d_in[13];
  const float* conv2_W = (const float*)d_in[14];
  const float* conv2_b = (const float*)d_in[15];
  const float* fc2_W = (const float*)d_in[16];
  const float* fc2_b = (const float*)d_in[17];
  const float* final_W = (const float*)d_in[18];
  const float* final_b = (const float*)d_in[19];
  float* out = (float*)d_out;

  const int N = in_sizes[2];      // 10000
  const int E = in_sizes[1] / 2;  // 80000
  const int A = E + N;

  size_t off_b = 0;
  auto alloc = [&](size_t bytes) -> void* {
    void* p = (char*)d_ws + off_b;
    off_b += (bytes + 255) & ~(size_t)255;
    return p;
  };
  unsigned short* xbf1 = (unsigned short*)alloc((size_t)N * FDIM * 2);
  unsigned short* xbf2 = (unsigned short*)alloc((size_t)N * FDIM * 2);
  unsigned short* hbf1 = (unsigned short*)alloc((size_t)N * FDIM * 2);
  unsigned short* hbf2 = (unsigned short*)alloc((size_t)N * FDIM * 2);
  unsigned short* Wt1 = (unsigned short*)alloc((size_t)FDIM * FDIM * 2);
  unsigned short* Wt2 = (unsigned short*)alloc((size_t)FDIM * FDIM * 2);
  int* deg1 = (int*)alloc(N * 4);
  int* deg2 = (int*)alloc(N * 4);
  int* cnt1 = (int*)alloc(NGRAPH * 4);
  int* cnt2 = (int*)alloc(NGRAPH * 4);
  int* gstart1 = (int*)alloc(NGRAPH * 4);
  int* gstart2 = (int*)alloc(NGRAPH * 4);
  int* off1 = (int*)alloc((N + 1) * 4);
  int* off2 = (int*)alloc((N + 1) * 4);
  int* cur1 = (int*)alloc(N * 4);
  int* cur2 = (int*)alloc(N * 4);
  float* dinv1 = (float*)alloc(N * 4);
  float* dinv2 = (float*)alloc(N * 4);
  int* adjsrc1 = (int*)alloc((size_t)A * 4);
  int* adjsrc2 = (int*)alloc((size_t)A * 4);
  float* adjw1 = (float*)alloc((size_t)A * 4);
  float* adjw2 = (float*)alloc((size_t)A * 4);
  float* pool4_1 = (float*)alloc((size_t)QN * NGRAPH * FDIM * 4);
  float* pool4_2 = (float*)alloc((size_t)QN * NGRAPH * FDIM * 4);

  const int T = 256;
  int gE = (E + T - 1) / T;                 // 313
  int n8 = N * FDIM / 8;
  int nxb = (n8 + T - 1) / T;               // 5000
  int mt = (N + BM - 1) / BM;               // 40
  dim3 gPrepCast(gE + nxb + 256, 2);
  dim3 gFillGemm(FILLB + mt * 8, 2);        // 320 + 320 (both mult-of-8 ranges)
  dim3 gAgg(FCH * NGRAPH * QN, 2);

  hipMemsetAsync(deg1, 0, (size_t)N * 4, stream);
  hipMemsetAsync(deg2, 0, (size_t)N * 4, stream);
  k_prep_cast<<<gPrepCast, T, 0, stream>>>(ei1, ei2, deg1, deg2,
                                           (const float4*)x1, (const float4*)x2,
                                           conv1_W, conv2_W,
                                           (u16x8*)xbf1, (u16x8*)xbf2, Wt1, Wt2,
                                           E, n8, gE, nxb);
  k_scan<<<3, SCAN_T, 0, stream>>>(deg1, deg2, off1, off2, cur1, cur2, dinv1, dinv2,
                                   batch1, batch2, cnt1, gstart1, cnt2, gstart2, N);
  k_fill_gemm<<<gFillGemm, T, 0, stream>>>(ei1, ei2, cur1, cur2, dinv1, dinv2,
                                           adjsrc1, adjsrc2, adjw1, adjw2,
                                           xbf1, xbf2, Wt1, Wt2, hbf1, hbf2,
                                           E, N, N);
  k_aggpool<<<gAgg, T, 0, stream>>>(hbf1, hbf2, off1, off2, adjsrc1, adjsrc2,
                                    adjw1, adjw2, conv1_b, conv2_b,
                                    cnt1, cnt2, gstart1, gstart2, pool4_1, pool4_2);
  k_fc_final<<<NGRAPH, T, 0, stream>>>(pool4_1, pool4_2, fc1_W, fc2_W, fc1_b, fc2_b,
                                       final_W, final_b, out);
}

// Round 2
// 324.027 us; speedup vs baseline: 1.0533x; 1.0533x over previous
//
#include <hip/hip_runtime.h>
#include <cstdint>
#include <cstddef>

#define FDIM 1024   // feature dim F
#define DDIM 128    // fc out dim D
#define NGRAPH 64   // num graphs B
#define FCH 8       // feature chunks (XCD-local gather)
#define QN 4        // node quarters per graph
#define FILLB 320   // fill-block range in k_fill_gemm (mult of 8)

#define AS1 __attribute__((address_space(1)))
#define AS3 __attribute__((address_space(3)))

typedef float f32x4 __attribute__((ext_vector_type(4)));
typedef short s16x8 __attribute__((ext_vector_type(8)));
typedef unsigned short u16x8 __attribute__((ext_vector_type(8)));

__device__ __forceinline__ unsigned short f2bf(float f) {
  unsigned int x = __float_as_uint(f);
  unsigned int r = (x + 0x7fffu + ((x >> 16) & 1u)) >> 16;  // RNE
  return (unsigned short)r;
}
__device__ __forceinline__ float bflo(unsigned int v) {
  return __uint_as_float(v << 16);
}
__device__ __forceinline__ float bfhi(unsigned int v) {
  return __uint_as_float(v & 0xffff0000u);
}

__device__ __forceinline__ int lower_bound(const int* a, int n, int v) {
  int lo = 0, hi = n;
  while (lo < hi) {
    int mid = (lo + hi) >> 1;
    if (a[mid] < v) lo = mid + 1; else hi = mid;
  }
  return lo;
}

// ---------------------------------------------------------------------------
// prep+cast (merged, grid.y = branch):
//   x in [0, gE)            : in-degree atomics (deg pre-zeroed by memset;
//                             self-loop +1 is applied inside k_scan)
//   x in [gE, gE+nxb)       : x fp32 -> bf16 cast, 32B in / 16B out per thread
//   x in [gE+nxb, +256)     : W cast+transpose (64x64 LDS tiles)
// ---------------------------------------------------------------------------
__global__ __launch_bounds__(256) void k_prep_cast(const int* __restrict__ ei1,
                                                   const int* __restrict__ ei2,
                                                   int* deg1, int* deg2,
                                                   const float4* __restrict__ x1,
                                                   const float4* __restrict__ x2,
                                                   const float* __restrict__ W1,
                                                   const float* __restrict__ W2,
                                                   u16x8* xb1, u16x8* xb2,
                                                   unsigned short* Wt1, unsigned short* Wt2,
                                                   int E, int n8, int gE, int nxb) {
  __shared__ unsigned short tile[64][65];
  int br = blockIdx.y;
  int x = blockIdx.x, t = threadIdx.x;
  if (x < gE) {
    const int* ei = br ? ei2 : ei1;
    int* deg = br ? deg2 : deg1;
    int i = x * 256 + t;
    if (i < E) atomicAdd(&deg[ei[E + i]], 1);
  } else if (x < gE + nxb) {
    const float4* xx = br ? x2 : x1;
    u16x8* xb = br ? xb2 : xb1;
    int i = (x - gE) * 256 + t;
    if (i < n8) {
      float4 v0 = xx[2 * i];
      float4 v1 = xx[2 * i + 1];
      u16x8 o;
      o[0] = f2bf(v0.x); o[1] = f2bf(v0.y); o[2] = f2bf(v0.z); o[3] = f2bf(v0.w);
      o[4] = f2bf(v1.x); o[5] = f2bf(v1.y); o[6] = f2bf(v1.z); o[7] = f2bf(v1.w);
      xb[i] = o;
    }
  } else {
    const float* W = br ? W2 : W1;
    unsigned short* Wt = br ? Wt2 : Wt1;
    int tid16 = x - gE - nxb;        // 0..255
    int kb = tid16 >> 4, nb = tid16 & 15;
    int tn = t & 63, tg = t >> 6;
    #pragma unroll
    for (int r = 0; r < 16; ++r) {
      int kk = tg * 16 + r;
      tile[kk][tn] = f2bf(W[(size_t)(kb * 64 + kk) * FDIM + nb * 64 + tn]);
    }
    __syncthreads();
    #pragma unroll
    for (int r = 0; r < 16; ++r) {
      int nn = tg * 16 + r;
      Wt[(size_t)(nb * 64 + nn) * FDIM + kb * 64 + tn] = tile[tn][nn];
    }
  }
}

// ---------------------------------------------------------------------------
// scan (merged): blockIdx.x = branch (0/1); block 2 = cnt/gstart binary search.
// deg holds in-degree only; self-loop +1 applied here (replaces k_init).
// ---------------------------------------------------------------------------
#define SCAN_T 1024
#define SCAN_PER 16
__global__ __launch_bounds__(SCAN_T) void k_scan(const int* __restrict__ deg1,
                                                 const int* __restrict__ deg2,
                                                 int* off1, int* off2,
                                                 int* cur1, int* cur2,
                                                 float* dinv1, float* dinv2,
                                                 const int* __restrict__ batch1,
                                                 const int* __restrict__ batch2,
                                                 int* cnt1, int* gstart1,
                                                 int* cnt2, int* gstart2, int n) {
  if (blockIdx.x == 2) {
    int t = threadIdx.x;
    if (t < 128) {
      const int* batch = (t < NGRAPH) ? batch1 : batch2;
      int* cnt = (t < NGRAPH) ? cnt1 : cnt2;
      int* gstart = (t < NGRAPH) ? gstart1 : gstart2;
      int g = t & (NGRAPH - 1);
      int lo = lower_bound(batch, n, g);
      int hi = lower_bound(batch, n, g + 1);
      gstart[g] = lo;
      cnt[g] = hi - lo;
    }
    return;
  }
  const int* deg = blockIdx.x ? deg2 : deg1;
  int* off = blockIdx.x ? off2 : off1;
  int* cur = blockIdx.x ? cur2 : cur1;
  float* dinv = blockIdx.x ? dinv2 : dinv1;
  __shared__ int sums[SCAN_T];
  int t = threadIdx.x;
  int base = t * SCAN_PER;
  int local[SCAN_PER];
  int s = 0;
  #pragma unroll
  for (int i = 0; i < SCAN_PER; ++i) {
    int idx = base + i;
    int d = (idx < n) ? (deg[idx] + 1) : 0;   // +1 = self-loop
    local[i] = s;
    s += d;
    if (idx < n) dinv[idx] = rsqrtf((float)d);
  }
  sums[t] = s;
  __syncthreads();
  for (int o = 1; o < SCAN_T; o <<= 1) {
    int v = (t >= o) ? sums[t - o] : 0;
    __syncthreads();
    sums[t] += v;
    __syncthreads();
  }
  int basesum = (t > 0) ? sums[t - 1] : 0;
  #pragma unroll
  for (int i = 0; i < SCAN_PER; ++i) {
    int idx = base + i;
    if (idx < n) { int o = basesum + local[i]; off[idx] = o; cur[idx] = o; }
  }
  if (t == SCAN_T - 1) off[n] = sums[SCAN_T - 1];
}

// ---------------------------------------------------------------------------
// fill+gemm (merged, grid.y = branch):
//   x in [0, FILLB)  : CSR fill (latency-bound atomics)
//   x in [FILLB, +mt*8) : bf16 MFMA GEMM, 128x128 tile / BK=32 (R6 config,
//   known-good: 64B LDS rows -> benign conflicts, 16KB LDS, ~136 regs),
//   XCD-aware swizzle. launch_bounds(,3) to allow 3 blocks/CU.
// ---------------------------------------------------------------------------
__global__ __launch_bounds__(256, 3) void k_fill_gemm(const int* __restrict__ ei1,
                                                      const int* __restrict__ ei2,
                                                      int* cur1, int* cur2,
                                                      const float* __restrict__ dinv1,
                                                      const float* __restrict__ dinv2,
                                                      int* adjsrc1, int* adjsrc2,
                                                      float* adjw1, float* adjw2,
                                                      const unsigned short* __restrict__ A1,
                                                      const unsigned short* __restrict__ A2,
                                                      const unsigned short* __restrict__ B1,
                                                      const unsigned short* __restrict__ B2,
                                                      unsigned short* __restrict__ C1,
                                                      unsigned short* __restrict__ C2,
                                                      int E, int N, int M) {
  __shared__ unsigned short sm[8192];  // gemm: As [0,4096) 128x32 ; Bs [4096,8192)
  int br = blockIdx.y;
  if (blockIdx.x < FILLB) {
    const int* ei = br ? ei2 : ei1;
    int* cur = br ? cur2 : cur1;
    const float* dinv = br ? dinv2 : dinv1;
    int* adjsrc = br ? adjsrc2 : adjsrc1;
    float* adjw = br ? adjw2 : adjw1;
    int i = blockIdx.x * 256 + threadIdx.x;
    if (i < E) {
      int s = ei[i];
      int d = ei[E + i];
      int p = atomicAdd(&cur[d], 1);
      adjsrc[p] = s;
      adjw[p] = dinv[s] * dinv[d];
    }
    if (i < N) {
      int p = atomicAdd(&cur[i], 1);
      adjsrc[p] = i;
      adjw[p] = dinv[i] * dinv[i];
    }
    return;
  }
  // ---- GEMM path (R6 128x128 config) ----
  const unsigned short* A = br ? A2 : A1;
  const unsigned short* Bt = br ? B2 : B1;
  unsigned short* C = br ? C2 : C1;
  const int K = FDIM;
  int tid = threadIdx.x;
  int w = tid >> 6, lane = tid & 63;
  int wm = w >> 1, wn = w & 1;

  int bx = blockIdx.x - FILLB;                 // 0 .. mt*8-1
  int per_xcd = (gridDim.x - FILLB) >> 3;
  int l = (bx & 7) * per_xcd + (bx >> 3);
  int m0 = (l >> 3) * 128;                     // nt == 8
  int n0 = (l & 7) * 128;

  int sub = lane >> 2;
  int kq = lane & 3;

  f32x4 acc[4][4];
  #pragma unroll
  for (int i = 0; i < 4; ++i)
    #pragma unroll
    for (int j = 0; j < 4; ++j)
      acc[i][j] = (f32x4){0.f, 0.f, 0.f, 0.f};

  for (int k0 = 0; k0 < K; k0 += 32) {
    #pragma unroll
    for (int j = 0; j < 2; ++j) {
      int chunk = w * 2 + j;
      int ra = m0 + chunk * 16 + sub;
      if (ra > M - 1) ra = M - 1;
      const unsigned short* ga = A + (size_t)ra * K + k0 + kq * 8;
      __builtin_amdgcn_global_load_lds((const AS1 unsigned int*)ga,
                                       (AS3 unsigned int*)&sm[chunk * 512], 16, 0, 0);
      int rb = n0 + chunk * 16 + sub;
      const unsigned short* gb = Bt + (size_t)rb * K + k0 + kq * 8;
      __builtin_amdgcn_global_load_lds((const AS1 unsigned int*)gb,
                                       (AS3 unsigned int*)&sm[4096 + chunk * 512], 16, 0, 0);
    }
    __syncthreads();
    s16x8 af[4], bfr[4];
    #pragma unroll
    for (int i = 0; i < 4; ++i) {
      int rowa = wm * 64 + i * 16 + (lane & 15);
      af[i] = *(const s16x8*)&sm[rowa * 32 + (lane >> 4) * 8];
      int rowb = wn * 64 + i * 16 + (lane & 15);
      bfr[i] = *(const s16x8*)&sm[4096 + rowb * 32 + (lane >> 4) * 8];
    }
    #pragma unroll
    for (int i = 0; i < 4; ++i)
      #pragma unroll
      for (int j = 0; j < 4; ++j)
        acc[i][j] = __builtin_amdgcn_mfma_f32_16x16x32_bf16(af[i], bfr[j], acc[i][j], 0, 0, 0);
    __syncthreads();
  }

  #pragma unroll
  for (int i = 0; i < 4; ++i) {
    int row_base = m0 + wm * 64 + i * 16 + (lane >> 4) * 4;
    #pragma unroll
    for (int j = 0; j < 4; ++j) {
      int col = n0 + wn * 64 + j * 16 + (lane & 15);
      #pragma unroll
      for (int r = 0; r < 4; ++r) {
        int row = row_base + r;
        if (row < M) C[(size_t)row * FDIM + col] = f2bf(acc[i][j][r]);
      }
    }
  }
}

// ---------------------------------------------------------------------------
// aggpool v4 (XCD-local, atomic-free): each (g,chunk,q) block writes its
// partial to pool4[q][g][f] with plain stores; fc sums partials.
// chunk == blockIdx.x & 7 == XCD id -> per-XCD gather set ~2.6MB (L2-resident)
// ---------------------------------------------------------------------------
__global__ __launch_bounds__(256) void k_aggpool(const unsigned short* __restrict__ h1,
                                                 const unsigned short* __restrict__ h2,
                                                 const int* __restrict__ off1,
                                                 const int* __restrict__ off2,
                                                 const int* __restrict__ adjsrc1,
                                                 const int* __restrict__ adjsrc2,
                                                 const float* __restrict__ adjw1,
                                                 const float* __restrict__ adjw2,
                                                 const float* __restrict__ bias1,
                                                 const float* __restrict__ bias2,
                                                 const int* __restrict__ cnt1,
                                                 const int* __restrict__ cnt2,
                                                 const int* __restrict__ gstart1,
                                                 const int* __restrict__ gstart2,
                                                 float* pool4_1, float* pool4_2) {
  int br = blockIdx.y;
  const unsigned short* h = br ? h2 : h1;
  const int* off = br ? off2 : off1;
  const int* adjsrc = br ? adjsrc2 : adjsrc1;
  const float* adjw = br ? adjw2 : adjw1;
  const float* bias = br ? bias2 : bias1;
  const int* cnt = br ? cnt2 : cnt1;
  const int* gstart = br ? gstart2 : gstart1;
  float* pool4 = br ? pool4_2 : pool4_1;

  int x = blockIdx.x;
  int chunk = x & (FCH - 1);
  int r = x >> 3;
  int g = r & (NGRAPH - 1);
  int q = r >> 6;

  int t = threadIdx.x;
  int grp = t >> 6, lane = t & 63;

  int n = cnt[g];
  int start = gstart[g];
  int per = (n + QN - 1) / QN;
  int v0 = start + q * per;
  int v1 = min(start + n, v0 + per);

  int colbase = chunk * 128 + lane * 2;
  const unsigned short* hc = h + colbase;
  float2 b2 = *(const float2*)(bias + colbase);
  float s0 = 0.f, s1 = 0.f;

  for (int v = v0 + grp; v < v1; v += 4) {
    int pb = off[v], pe = off[v + 1];
    float a0 = 0.f, a1 = 0.f;
    for (int pbb = pb; pbb < pe; pbb += 64) {
      int m = min(64, pe - pbb);
      int lp = pbb + ((lane < m) ? lane : (m - 1));
      int vs = adjsrc[lp];
      float vw = adjw[lp];
      int j = 0;
      for (; j + 4 <= m; j += 4) {
        int i0 = __shfl(vs, j),     i1 = __shfl(vs, j + 1);
        int i2 = __shfl(vs, j + 2), i3 = __shfl(vs, j + 3);
        float w0 = __shfl(vw, j),     w1 = __shfl(vw, j + 1);
        float w2 = __shfl(vw, j + 2), w3 = __shfl(vw, j + 3);
        unsigned int h0 = *(const unsigned int*)(hc + ((size_t)i0 << 10));
        unsigned int hv1 = *(const unsigned int*)(hc + ((size_t)i1 << 10));
        unsigned int hv2 = *(const unsigned int*)(hc + ((size_t)i2 << 10));
        unsigned int hv3 = *(const unsigned int*)(hc + ((size_t)i3 << 10));
        a0 += w0 * bflo(h0);  a1 += w0 * bfhi(h0);
        a0 += w1 * bflo(hv1); a1 += w1 * bfhi(hv1);
        a0 += w2 * bflo(hv2); a1 += w2 * bfhi(hv2);
        a0 += w3 * bflo(hv3); a1 += w3 * bfhi(hv3);
      }
      for (; j < m; ++j) {
        int i0 = __shfl(vs, j);
        float w0 = __shfl(vw, j);
        unsigned int h0 = *(const unsigned int*)(hc + ((size_t)i0 << 10));
        a0 += w0 * bflo(h0);
        a1 += w0 * bfhi(h0);
      }
    }
    a0 += b2.x; a1 += b2.y;
    s0 += (a0 >= 0.f) ? a0 : 0.01f * a0;
    s1 += (a1 >= 0.f) ? a1 : 0.01f * a1;
  }

  __shared__ float sm[4][128];
  sm[grp][lane * 2] = s0;
  sm[grp][lane * 2 + 1] = s1;
  __syncthreads();
  if (t < 128) {
    float sum = sm[0][t] + sm[1][t] + sm[2][t] + sm[3][t];
    float ic = 1.0f / fmaxf((float)n, 1.0f);
    pool4[((size_t)(q * NGRAPH + g)) * FDIM + chunk * 128 + t] = sum * ic;
  }
}

// ---------------------------------------------------------------------------
// fc+final (merged): one block per graph, 256 threads.
// t<128 -> branch1 fc row, t>=128 -> branch2; then dot with final_W + reduce.
// ---------------------------------------------------------------------------
__global__ __launch_bounds__(256) void k_fc_final(const float* __restrict__ pool4_1,
                                                  const float* __restrict__ pool4_2,
                                                  const float* __restrict__ W1,
                                                  const float* __restrict__ W2,
                                                  const float* __restrict__ b1,
                                                  const float* __restrict__ b2,
                                                  const float* __restrict__ fW,
                                                  const float* __restrict__ fb,
                                                  float* __restrict__ out) {
  int g = blockIdx.x;
  int t = threadIdx.x;
  int half = t >> 7;
  int j = t & 127;
  const float* pool4 = half ? pool4_2 : pool4_1;
  const float* W = half ? W2 : W1;
  const float* b = half ? b2 : b1;
  __shared__ float xs[2][FDIM];
  for (int k = j; k < FDIM; k += DDIM) {
    float v = 0.f;
    #pragma unroll
    for (int q = 0; q < QN; ++q)
      v += pool4[((size_t)(q * NGRAPH + g)) * FDIM + k];
    xs[half][k] = v;
  }
  __syncthreads();
  float acc = b[j];
  for (int k = 0; k < FDIM; ++k) acc += xs[half][k] * W[(size_t)k * DDIM + j];
  acc = (acc >= 0.f) ? acc : 0.01f * acc;
  float c = acc * fW[half * DDIM + j];
  #pragma unroll
  for (int o = 32; o > 0; o >>= 1) c += __shfl_down(c, o);
  __shared__ float ws[4];
  if ((t & 63) == 0) ws[t >> 6] = c;
  __syncthreads();
  if (t == 0) out[g] = ws[0] + ws[1] + ws[2] + ws[3] + fb[0];
}

// ---------------------------------------------------------------------------
extern "C" void kernel_launch(void* const* d_in, const int* in_sizes, int n_in,
                              void* d_out, int out_size, void* d_ws, size_t ws_size,
                              hipStream_t stream) {
  const float* x1 = (const float*)d_in[0];
  const int* ei1 = (const int*)d_in[1];
  const int* batch1 = (const int*)d_in[2];
  const float* x2 = (const float*)d_in[3];
  const int* ei2 = (const int*)d_in[4];
  const int* batch2 = (const int*)d_in[5];
  const float* conv1_W = (const float*)d_in[10];
  const float* conv1_b = (const float*)d_in[11];
  const float* fc1_W = (const float*)d_in[12];
  const float* fc1_b = (const float*)d_in[13];
  const float* conv2_W = (const float*)d_in[14];
  const float* conv2_b = (const float*)d_in[15];
  const float* fc2_W = (const float*)d_in[16];
  const float* fc2_b = (const float*)d_in[17];
  const float* final_W = (const float*)d_in[18];
  const float* final_b = (const float*)d_in[19];
  float* out = (float*)d_out;

  const int N = in_sizes[2];      // 10000
  const int E = in_sizes[1] / 2;  // 80000
  const int A = E + N;

  size_t off_b = 0;
  auto alloc = [&](size_t bytes) -> void* {
    void* p = (char*)d_ws + off_b;
    off_b += (bytes + 255) & ~(size_t)255;
    return p;
  };
  unsigned short* xbf1 = (unsigned short*)alloc((size_t)N * FDIM * 2);
  unsigned short* xbf2 = (unsigned short*)alloc((size_t)N * FDIM * 2);
  unsigned short* hbf1 = (unsigned short*)alloc((size_t)N * FDIM * 2);
  unsigned short* hbf2 = (unsigned short*)alloc((size_t)N * FDIM * 2);
  unsigned short* Wt1 = (unsigned short*)alloc((size_t)FDIM * FDIM * 2);
  unsigned short* Wt2 = (unsigned short*)alloc((size_t)FDIM * FDIM * 2);
  int* deg1 = (int*)alloc(N * 4);
  int* deg2 = (int*)alloc(N * 4);
  int* cnt1 = (int*)alloc(NGRAPH * 4);
  int* cnt2 = (int*)alloc(NGRAPH * 4);
  int* gstart1 = (int*)alloc(NGRAPH * 4);
  int* gstart2 = (int*)alloc(NGRAPH * 4);
  int* off1 = (int*)alloc((N + 1) * 4);
  int* off2 = (int*)alloc((N + 1) * 4);
  int* cur1 = (int*)alloc(N * 4);
  int* cur2 = (int*)alloc(N * 4);
  float* dinv1 = (float*)alloc(N * 4);
  float* dinv2 = (float*)alloc(N * 4);
  int* adjsrc1 = (int*)alloc((size_t)A * 4);
  int* adjsrc2 = (int*)alloc((size_t)A * 4);
  float* adjw1 = (float*)alloc((size_t)A * 4);
  float* adjw2 = (float*)alloc((size_t)A * 4);
  float* pool4_1 = (float*)alloc((size_t)QN * NGRAPH * FDIM * 4);
  float* pool4_2 = (float*)alloc((size_t)QN * NGRAPH * FDIM * 4);

  const int T = 256;
  int gE = (E + T - 1) / T;                 // 313
  int n8 = N * FDIM / 8;
  int nxb = (n8 + T - 1) / T;               // 5000
  int mt = (N + 127) / 128;                 // 79
  dim3 gPrepCast(gE + nxb + 256, 2);
  dim3 gFillGemm(FILLB + mt * 8, 2);        // 320 + 632 (both mult-of-8 ranges)
  dim3 gAgg(FCH * NGRAPH * QN, 2);

  hipMemsetAsync(deg1, 0, (size_t)N * 4, stream);
  hipMemsetAsync(deg2, 0, (size_t)N * 4, stream);
  k_prep_cast<<<gPrepCast, T, 0, stream>>>(ei1, ei2, deg1, deg2,
                                           (const float4*)x1, (const float4*)x2,
                                           conv1_W, conv2_W,
                                           (u16x8*)xbf1, (u16x8*)xbf2, Wt1, Wt2,
                                           E, n8, gE, nxb);
  k_scan<<<3, SCAN_T, 0, stream>>>(deg1, deg2, off1, off2, cur1, cur2, dinv1, dinv2,
                                   batch1, batch2, cnt1, gstart1, cnt2, gstart2, N);
  k_fill_gemm<<<gFillGemm, T, 0, stream>>>(ei1, ei2, cur1, cur2, dinv1, dinv2,
                                           adjsrc1, adjsrc2, adjw1, adjw2,
                                           xbf1, xbf2, Wt1, Wt2, hbf1, hbf2,
                                           E, N, N);
  k_aggpool<<<gAgg, T, 0, stream>>>(hbf1, hbf2, off1, off2, adjsrc1, adjsrc2,
                                    adjw1, adjw2, conv1_b, conv2_b,
                                    cnt1, cnt2, gstart1, gstart2, pool4_1, pool4_2);
  k_fc_final<<<NGRAPH, T, 0, stream>>>(pool4_1, pool4_2, fc1_W, fc2_W, fc1_b, fc2_b,
                                       final_W, final_b, out);
}

// Round 3
// 317.080 us; speedup vs baseline: 1.0764x; 1.0219x over previous
//
#include <hip/hip_runtime.h>
#include <cstdint>
#include <cstddef>

#define FDIM 1024   // feature dim F
#define DDIM 128    // fc out dim D
#define NGRAPH 64   // num graphs B
#define FCH 8       // feature chunks (XCD-local gather)
#define QN 4        // node quarters per graph
#define FILLB 320   // fill-block range in k_fill_gemm (mult of 8)

#define AS1 __attribute__((address_space(1)))
#define AS3 __attribute__((address_space(3)))

typedef float f32x4 __attribute__((ext_vector_type(4)));
typedef short s16x8 __attribute__((ext_vector_type(8)));
typedef unsigned short u16x8 __attribute__((ext_vector_type(8)));

__device__ __forceinline__ unsigned short f2bf(float f) {
  unsigned int x = __float_as_uint(f);
  unsigned int r = (x + 0x7fffu + ((x >> 16) & 1u)) >> 16;  // RNE
  return (unsigned short)r;
}
__device__ __forceinline__ float bflo(unsigned int v) {
  return __uint_as_float(v << 16);
}
__device__ __forceinline__ float bfhi(unsigned int v) {
  return __uint_as_float(v & 0xffff0000u);
}

__device__ __forceinline__ int lower_bound(const int* a, int n, int v) {
  int lo = 0, hi = n;
  while (lo < hi) {
    int mid = (lo + hi) >> 1;
    if (a[mid] < v) lo = mid + 1; else hi = mid;
  }
  return lo;
}

// ---------------------------------------------------------------------------
// prep+cast (merged, grid.y = branch):
//   x in [0, gE)            : in-degree atomics (deg pre-zeroed by memset;
//                             self-loop +1 is applied inside k_scan)
//   x in [gE, gE+nxb)       : x fp32 -> bf16 cast, 32B in / 16B out per thread
//   x in [gE+nxb, +256)     : W cast+transpose (64x64 LDS tiles)
// ---------------------------------------------------------------------------
__global__ __launch_bounds__(256) void k_prep_cast(const int* __restrict__ ei1,
                                                   const int* __restrict__ ei2,
                                                   int* deg1, int* deg2,
                                                   const float4* __restrict__ x1,
                                                   const float4* __restrict__ x2,
                                                   const float* __restrict__ W1,
                                                   const float* __restrict__ W2,
                                                   u16x8* xb1, u16x8* xb2,
                                                   unsigned short* Wt1, unsigned short* Wt2,
                                                   int E, int n8, int gE, int nxb) {
  __shared__ unsigned short tile[64][65];
  int br = blockIdx.y;
  int x = blockIdx.x, t = threadIdx.x;
  if (x < gE) {
    const int* ei = br ? ei2 : ei1;
    int* deg = br ? deg2 : deg1;
    int i = x * 256 + t;
    if (i < E) atomicAdd(&deg[ei[E + i]], 1);
  } else if (x < gE + nxb) {
    const float4* xx = br ? x2 : x1;
    u16x8* xb = br ? xb2 : xb1;
    int i = (x - gE) * 256 + t;
    if (i < n8) {
      float4 v0 = xx[2 * i];
      float4 v1 = xx[2 * i + 1];
      u16x8 o;
      o[0] = f2bf(v0.x); o[1] = f2bf(v0.y); o[2] = f2bf(v0.z); o[3] = f2bf(v0.w);
      o[4] = f2bf(v1.x); o[5] = f2bf(v1.y); o[6] = f2bf(v1.z); o[7] = f2bf(v1.w);
      xb[i] = o;
    }
  } else {
    const float* W = br ? W2 : W1;
    unsigned short* Wt = br ? Wt2 : Wt1;
    int tid16 = x - gE - nxb;        // 0..255
    int kb = tid16 >> 4, nb = tid16 & 15;
    int tn = t & 63, tg = t >> 6;
    #pragma unroll
    for (int r = 0; r < 16; ++r) {
      int kk = tg * 16 + r;
      tile[kk][tn] = f2bf(W[(size_t)(kb * 64 + kk) * FDIM + nb * 64 + tn]);
    }
    __syncthreads();
    #pragma unroll
    for (int r = 0; r < 16; ++r) {
      int nn = tg * 16 + r;
      Wt[(size_t)(nb * 64 + nn) * FDIM + kb * 64 + tn] = tile[tn][nn];
    }
  }
}

// ---------------------------------------------------------------------------
// scan (merged): blockIdx.x = branch (0/1); block 2 = cnt/gstart binary search.
// ---------------------------------------------------------------------------
#define SCAN_T 1024
#define SCAN_PER 16
__global__ __launch_bounds__(SCAN_T) void k_scan(const int* __restrict__ deg1,
                                                 const int* __restrict__ deg2,
                                                 int* off1, int* off2,
                                                 int* cur1, int* cur2,
                                                 float* dinv1, float* dinv2,
                                                 const int* __restrict__ batch1,
                                                 const int* __restrict__ batch2,
                                                 int* cnt1, int* gstart1,
                                                 int* cnt2, int* gstart2, int n) {
  if (blockIdx.x == 2) {
    int t = threadIdx.x;
    if (t < 128) {
      const int* batch = (t < NGRAPH) ? batch1 : batch2;
      int* cnt = (t < NGRAPH) ? cnt1 : cnt2;
      int* gstart = (t < NGRAPH) ? gstart1 : gstart2;
      int g = t & (NGRAPH - 1);
      int lo = lower_bound(batch, n, g);
      int hi = lower_bound(batch, n, g + 1);
      gstart[g] = lo;
      cnt[g] = hi - lo;
    }
    return;
  }
  const int* deg = blockIdx.x ? deg2 : deg1;
  int* off = blockIdx.x ? off2 : off1;
  int* cur = blockIdx.x ? cur2 : cur1;
  float* dinv = blockIdx.x ? dinv2 : dinv1;
  __shared__ int sums[SCAN_T];
  int t = threadIdx.x;
  int base = t * SCAN_PER;
  int local[SCAN_PER];
  int s = 0;
  #pragma unroll
  for (int i = 0; i < SCAN_PER; ++i) {
    int idx = base + i;
    int d = (idx < n) ? (deg[idx] + 1) : 0;   // +1 = self-loop
    local[i] = s;
    s += d;
    if (idx < n) dinv[idx] = rsqrtf((float)d);
  }
  sums[t] = s;
  __syncthreads();
  for (int o = 1; o < SCAN_T; o <<= 1) {
    int v = (t >= o) ? sums[t - o] : 0;
    __syncthreads();
    sums[t] += v;
    __syncthreads();
  }
  int basesum = (t > 0) ? sums[t - 1] : 0;
  #pragma unroll
  for (int i = 0; i < SCAN_PER; ++i) {
    int idx = base + i;
    if (idx < n) { int o = basesum + local[i]; off[idx] = o; cur[idx] = o; }
  }
  if (t == SCAN_T - 1) off[n] = sums[SCAN_T - 1];
}

// ---------------------------------------------------------------------------
// fill+gemm (merged, grid.y = branch):
//   x in [0, FILLB)  : CSR fill (latency-bound atomics)
//   x in [FILLB, +mt*8) : bf16 MFMA GEMM, 128x128 tile / BK=32.
// R9: T4 counted-vmcnt pipeline — 3-deep circular LDS buffers (3x16KB),
// stage chunk kt+2 during compute of kt, s_waitcnt vmcnt(8) (never 0 in
// steady state), raw s_barrier (no compiler vmcnt(0) drain). T2 XOR-swizzle
// (unit ^= (row>>1)&3, both-sides: pre-swizzled global source + swizzled
// asm ds_read) kills the 8-way bank conflict. T5 setprio around MFMA.
// Race invariant: in-flight stages at any barrier target buffers
// {kt+1,kt+2}%3, never the buffer being read; write into (kt+2)%3 is fenced
// from its prior readers by the post-MFMA barrier of iteration kt-1.
// ---------------------------------------------------------------------------
__global__ __launch_bounds__(256, 3) void k_fill_gemm(const int* __restrict__ ei1,
                                                      const int* __restrict__ ei2,
                                                      int* cur1, int* cur2,
                                                      const float* __restrict__ dinv1,
                                                      const float* __restrict__ dinv2,
                                                      int* adjsrc1, int* adjsrc2,
                                                      float* adjw1, float* adjw2,
                                                      const unsigned short* __restrict__ A1,
                                                      const unsigned short* __restrict__ A2,
                                                      const unsigned short* __restrict__ B1,
                                                      const unsigned short* __restrict__ B2,
                                                      unsigned short* __restrict__ C1,
                                                      unsigned short* __restrict__ C2,
                                                      int E, int N, int M) {
  // 3 buffers x (A 128x32 + B 128x32) bf16 = 3 x 16KB = 48KB
  __shared__ unsigned short sm[24576];
  int br = blockIdx.y;
  if (blockIdx.x < FILLB) {
    const int* ei = br ? ei2 : ei1;
    int* cur = br ? cur2 : cur1;
    const float* dinv = br ? dinv2 : dinv1;
    int* adjsrc = br ? adjsrc2 : adjsrc1;
    float* adjw = br ? adjw2 : adjw1;
    int i = blockIdx.x * 256 + threadIdx.x;
    if (i < E) {
      int s = ei[i];
      int d = ei[E + i];
      int p = atomicAdd(&cur[d], 1);
      adjsrc[p] = s;
      adjw[p] = dinv[s] * dinv[d];
    }
    if (i < N) {
      int p = atomicAdd(&cur[i], 1);
      adjsrc[p] = i;
      adjw[p] = dinv[i] * dinv[i];
    }
    return;
  }
  // ---- GEMM path ----
  const unsigned short* A = br ? A2 : A1;
  const unsigned short* Bt = br ? B2 : B1;
  unsigned short* C = br ? C2 : C1;
  const int K = FDIM;
  int tid = threadIdx.x;
  int w = tid >> 6, lane = tid & 63;
  int wm = w >> 1, wn = w & 1;

  int bx = blockIdx.x - FILLB;                 // 0 .. mt*8-1
  int per_xcd = (gridDim.x - FILLB) >> 3;
  int l = (bx & 7) * per_xcd + (bx >> 3);
  int m0 = (l >> 3) * 128;                     // nt == 8
  int n0 = (l & 7) * 128;

  int la = lane & 15, u4 = lane >> 4;

  // --- staging addressing (pre-swizzled global source; linear LDS dest) ---
  // LDS 16B-slot s = w*128 + p*64 + lane; row r = s>>2; unit u' = s&3.
  // Logical k-unit stored there: c16 = u' ^ ((r>>1)&3) = (lane&3)^((lane>>3)&3).
  int rs = w * 32 + (lane >> 2);               // + p*16
  int c16 = (lane & 3) ^ ((lane >> 3) & 3);
  const unsigned short* gA0 = A + (size_t)min(m0 + rs, M - 1) * K + c16 * 8;
  const unsigned short* gA1 = A + (size_t)min(m0 + rs + 16, M - 1) * K + c16 * 8;
  const unsigned short* gB0 = Bt + (size_t)(n0 + rs) * K + c16 * 8;
  const unsigned short* gB1 = Bt + (size_t)(n0 + rs + 16) * K + c16 * 8;
  int lbA = w * 1024;                          // ushort idx within buffer (+p*512)

  // --- read addressing: slot unit = u4 ^ ((r>>1)&3) = u4 ^ ((la>>1)&3) ---
  int sw = ((la >> 1) & 3) ^ u4;
  unsigned raoff = (unsigned)((wm * 64 + la) * 32 + sw * 8);         // A frag 0
  unsigned rboff = (unsigned)(4096 + (wn * 64 + la) * 32 + sw * 8);  // B frag 0

  f32x4 acc[4][4];
  #pragma unroll
  for (int i = 0; i < 4; ++i)
    #pragma unroll
    for (int j = 0; j < 4; ++j)
      acc[i][j] = (f32x4){0.f, 0.f, 0.f, 0.f};

  auto STAGE = [&](int bb, int kc) {
    int kq = kc * 32;  // ushort advance per 32-K chunk (64B)
    int b0 = bb * 8192 + lbA;
    __builtin_amdgcn_global_load_lds((const AS1 unsigned int*)(gA0 + kq),
                                     (AS3 unsigned int*)&sm[b0], 16, 0, 0);
    __builtin_amdgcn_global_load_lds((const AS1 unsigned int*)(gA1 + kq),
                                     (AS3 unsigned int*)&sm[b0 + 512], 16, 0, 0);
    __builtin_amdgcn_global_load_lds((const AS1 unsigned int*)(gB0 + kq),
                                     (AS3 unsigned int*)&sm[b0 + 4096], 16, 0, 0);
    __builtin_amdgcn_global_load_lds((const AS1 unsigned int*)(gB1 + kq),
                                     (AS3 unsigned int*)&sm[b0 + 4096 + 512], 16, 0, 0);
  };

  auto COMPUTE = [&](int bb) {
    const AS3 unsigned short* pa = (const AS3 unsigned short*)&sm[0] + bb * 8192 + raoff;
    const AS3 unsigned short* pb = (const AS3 unsigned short*)&sm[0] + bb * 8192 + rboff;
    s16x8 a0, a1, a2, a3, b0, b1, b2, b3;
    asm volatile("ds_read_b128 %0, %1 offset:0"    : "=v"(a0) : "v"(pa));
    asm volatile("ds_read_b128 %0, %1 offset:1024" : "=v"(a1) : "v"(pa));
    asm volatile("ds_read_b128 %0, %1 offset:2048" : "=v"(a2) : "v"(pa));
    asm volatile("ds_read_b128 %0, %1 offset:3072" : "=v"(a3) : "v"(pa));
    asm volatile("ds_read_b128 %0, %1 offset:0"    : "=v"(b0) : "v"(pb));
    asm volatile("ds_read_b128 %0, %1 offset:1024" : "=v"(b1) : "v"(pb));
    asm volatile("ds_read_b128 %0, %1 offset:2048" : "=v"(b2) : "v"(pb));
    asm volatile("ds_read_b128 %0, %1 offset:3072" : "=v"(b3) : "v"(pb));
    asm volatile("s_waitcnt lgkmcnt(0)" ::: "memory");
    __builtin_amdgcn_sched_barrier(0);
    __builtin_amdgcn_s_setprio(1);
    acc[0][0] = __builtin_amdgcn_mfma_f32_16x16x32_bf16(a0, b0, acc[0][0], 0, 0, 0);
    acc[0][1] = __builtin_amdgcn_mfma_f32_16x16x32_bf16(a0, b1, acc[0][1], 0, 0, 0);
    acc[0][2] = __builtin_amdgcn_mfma_f32_16x16x32_bf16(a0, b2, acc[0][2], 0, 0, 0);
    acc[0][3] = __builtin_amdgcn_mfma_f32_16x16x32_bf16(a0, b3, acc[0][3], 0, 0, 0);
    acc[1][0] = __builtin_amdgcn_mfma_f32_16x16x32_bf16(a1, b0, acc[1][0], 0, 0, 0);
    acc[1][1] = __builtin_amdgcn_mfma_f32_16x16x32_bf16(a1, b1, acc[1][1], 0, 0, 0);
    acc[1][2] = __builtin_amdgcn_mfma_f32_16x16x32_bf16(a1, b2, acc[1][2], 0, 0, 0);
    acc[1][3] = __builtin_amdgcn_mfma_f32_16x16x32_bf16(a1, b3, acc[1][3], 0, 0, 0);
    acc[2][0] = __builtin_amdgcn_mfma_f32_16x16x32_bf16(a2, b0, acc[2][0], 0, 0, 0);
    acc[2][1] = __builtin_amdgcn_mfma_f32_16x16x32_bf16(a2, b1, acc[2][1], 0, 0, 0);
    acc[2][2] = __builtin_amdgcn_mfma_f32_16x16x32_bf16(a2, b2, acc[2][2], 0, 0, 0);
    acc[2][3] = __builtin_amdgcn_mfma_f32_16x16x32_bf16(a2, b3, acc[2][3], 0, 0, 0);
    acc[3][0] = __builtin_amdgcn_mfma_f32_16x16x32_bf16(a3, b0, acc[3][0], 0, 0, 0);
    acc[3][1] = __builtin_amdgcn_mfma_f32_16x16x32_bf16(a3, b1, acc[3][1], 0, 0, 0);
    acc[3][2] = __builtin_amdgcn_mfma_f32_16x16x32_bf16(a3, b2, acc[3][2], 0, 0, 0);
    acc[3][3] = __builtin_amdgcn_mfma_f32_16x16x32_bf16(a3, b3, acc[3][3], 0, 0, 0);
    __builtin_amdgcn_s_setprio(0);
  };

  // prologue: chunks 0,1 into buffers 0,1
  STAGE(0, 0);
  STAGE(1, 1);
  int sb = 2, cb = 0;
  for (int kt = 0; kt < 30; ++kt) {           // K/32 = 32 chunks; main 30
    STAGE(sb, kt + 2);
    asm volatile("s_waitcnt vmcnt(8)" ::: "memory");
    __builtin_amdgcn_sched_barrier(0);
    __builtin_amdgcn_s_barrier();
    COMPUTE(cb);
    __builtin_amdgcn_s_barrier();
    sb = (sb == 2) ? 0 : sb + 1;
    cb = (cb == 2) ? 0 : cb + 1;
  }
  // tail: chunks 30 (cb), 31 (cb+1)
  asm volatile("s_waitcnt vmcnt(4)" ::: "memory");
  __builtin_amdgcn_sched_barrier(0);
  __builtin_amdgcn_s_barrier();
  COMPUTE(cb);
  __builtin_amdgcn_s_barrier();
  cb = (cb == 2) ? 0 : cb + 1;
  asm volatile("s_waitcnt vmcnt(0)" ::: "memory");
  __builtin_amdgcn_sched_barrier(0);
  __builtin_amdgcn_s_barrier();
  COMPUTE(cb);

  #pragma unroll
  for (int i = 0; i < 4; ++i) {
    int row_base = m0 + wm * 64 + i * 16 + (lane >> 4) * 4;
    #pragma unroll
    for (int j = 0; j < 4; ++j) {
      int col = n0 + wn * 64 + j * 16 + (lane & 15);
      #pragma unroll
      for (int r = 0; r < 4; ++r) {
        int row = row_base + r;
        if (row < M) C[(size_t)row * FDIM + col] = f2bf(acc[i][j][r]);
      }
    }
  }
}

// ---------------------------------------------------------------------------
// aggpool v4 (XCD-local, atomic-free)
// ---------------------------------------------------------------------------
__global__ __launch_bounds__(256) void k_aggpool(const unsigned short* __restrict__ h1,
                                                 const unsigned short* __restrict__ h2,
                                                 const int* __restrict__ off1,
                                                 const int* __restrict__ off2,
                                                 const int* __restrict__ adjsrc1,
                                                 const int* __restrict__ adjsrc2,
                                                 const float* __restrict__ adjw1,
                                                 const float* __restrict__ adjw2,
                                                 const float* __restrict__ bias1,
                                                 const float* __restrict__ bias2,
                                                 const int* __restrict__ cnt1,
                                                 const int* __restrict__ cnt2,
                                                 const int* __restrict__ gstart1,
                                                 const int* __restrict__ gstart2,
                                                 float* pool4_1, float* pool4_2) {
  int br = blockIdx.y;
  const unsigned short* h = br ? h2 : h1;
  const int* off = br ? off2 : off1;
  const int* adjsrc = br ? adjsrc2 : adjsrc1;
  const float* adjw = br ? adjw2 : adjw1;
  const float* bias = br ? bias2 : bias1;
  const int* cnt = br ? cnt2 : cnt1;
  const int* gstart = br ? gstart2 : gstart1;
  float* pool4 = br ? pool4_2 : pool4_1;

  int x = blockIdx.x;
  int chunk = x & (FCH - 1);
  int r = x >> 3;
  int g = r & (NGRAPH - 1);
  int q = r >> 6;

  int t = threadIdx.x;
  int grp = t >> 6, lane = t & 63;

  int n = cnt[g];
  int start = gstart[g];
  int per = (n + QN - 1) / QN;
  int v0 = start + q * per;
  int v1 = min(start + n, v0 + per);

  int colbase = chunk * 128 + lane * 2;
  const unsigned short* hc = h + colbase;
  float2 b2 = *(const float2*)(bias + colbase);
  float s0 = 0.f, s1 = 0.f;

  for (int v = v0 + grp; v < v1; v += 4) {
    int pb = off[v], pe = off[v + 1];
    float a0 = 0.f, a1 = 0.f;
    for (int pbb = pb; pbb < pe; pbb += 64) {
      int m = min(64, pe - pbb);
      int lp = pbb + ((lane < m) ? lane : (m - 1));
      int vs = adjsrc[lp];
      float vw = adjw[lp];
      int j = 0;
      for (; j + 4 <= m; j += 4) {
        int i0 = __shfl(vs, j),     i1 = __shfl(vs, j + 1);
        int i2 = __shfl(vs, j + 2), i3 = __shfl(vs, j + 3);
        float w0 = __shfl(vw, j),     w1 = __shfl(vw, j + 1);
        float w2 = __shfl(vw, j + 2), w3 = __shfl(vw, j + 3);
        unsigned int h0 = *(const unsigned int*)(hc + ((size_t)i0 << 10));
        unsigned int hv1 = *(const unsigned int*)(hc + ((size_t)i1 << 10));
        unsigned int hv2 = *(const unsigned int*)(hc + ((size_t)i2 << 10));
        unsigned int hv3 = *(const unsigned int*)(hc + ((size_t)i3 << 10));
        a0 += w0 * bflo(h0);  a1 += w0 * bfhi(h0);
        a0 += w1 * bflo(hv1); a1 += w1 * bfhi(hv1);
        a0 += w2 * bflo(hv2); a1 += w2 * bfhi(hv2);
        a0 += w3 * bflo(hv3); a1 += w3 * bfhi(hv3);
      }
      for (; j < m; ++j) {
        int i0 = __shfl(vs, j);
        float w0 = __shfl(vw, j);
        unsigned int h0 = *(const unsigned int*)(hc + ((size_t)i0 << 10));
        a0 += w0 * bflo(h0);
        a1 += w0 * bfhi(h0);
      }
    }
    a0 += b2.x; a1 += b2.y;
    s0 += (a0 >= 0.f) ? a0 : 0.01f * a0;
    s1 += (a1 >= 0.f) ? a1 : 0.01f * a1;
  }

  __shared__ float sm[4][128];
  sm[grp][lane * 2] = s0;
  sm[grp][lane * 2 + 1] = s1;
  __syncthreads();
  if (t < 128) {
    float sum = sm[0][t] + sm[1][t] + sm[2][t] + sm[3][t];
    float ic = 1.0f / fmaxf((float)n, 1.0f);
    pool4[((size_t)(q * NGRAPH + g)) * FDIM + chunk * 128 + t] = sum * ic;
  }
}

// ---------------------------------------------------------------------------
// fc+final (merged): one block per graph, 256 threads.
// ---------------------------------------------------------------------------
__global__ __launch_bounds__(256) void k_fc_final(const float* __restrict__ pool4_1,
                                                  const float* __restrict__ pool4_2,
                                                  const float* __restrict__ W1,
                                                  const float* __restrict__ W2,
                                                  const float* __restrict__ b1,
                                                  const float* __restrict__ b2,
                                                  const float* __restrict__ fW,
                                                  const float* __restrict__ fb,
                                                  float* __restrict__ out) {
  int g = blockIdx.x;
  int t = threadIdx.x;
  int half = t >> 7;
  int j = t & 127;
  const float* pool4 = half ? pool4_2 : pool4_1;
  const float* W = half ? W2 : W1;
  const float* b = half ? b2 : b1;
  __shared__ float xs[2][FDIM];
  for (int k = j; k < FDIM; k += DDIM) {
    float v = 0.f;
    #pragma unroll
    for (int q = 0; q < QN; ++q)
      v += pool4[((size_t)(q * NGRAPH + g)) * FDIM + k];
    xs[half][k] = v;
  }
  __syncthreads();
  float acc = b[j];
  for (int k = 0; k < FDIM; ++k) acc += xs[half][k] * W[(size_t)k * DDIM + j];
  acc = (acc >= 0.f) ? acc : 0.01f * acc;
  float c = acc * fW[half * DDIM + j];
  #pragma unroll
  for (int o = 32; o > 0; o >>= 1) c += __shfl_down(c, o);
  __shared__ float ws[4];
  if ((t & 63) == 0) ws[t >> 6] = c;
  __syncthreads();
  if (t == 0) out[g] = ws[0] + ws[1] + ws[2] + ws[3] + fb[0];
}

// ---------------------------------------------------------------------------
extern "C" void kernel_launch(void* const* d_in, const int* in_sizes, int n_in,
                              void* d_out, int out_size, void* d_ws, size_t ws_size,
                              hipStream_t stream) {
  const float* x1 = (const float*)d_in[0];
  const int* ei1 = (const int*)d_in[1];
  const int* batch1 = (const int*)d_in[2];
  const float* x2 = (const float*)d_in[3];
  const int* ei2 = (const int*)d_in[4];
  const int* batch2 = (const int*)d_in[5];
  const float* conv1_W = (const float*)d_in[10];
  const float* conv1_b = (const float*)d_in[11];
  const float* fc1_W = (const float*)d_in[12];
  const float* fc1_b = (const float*)d_in[13];
  const float* conv2_W = (const float*)d_in[14];
  const float* conv2_b = (const float*)d_in[15];
  const float* fc2_W = (const float*)d_in[16];
  const float* fc2_b = (const float*)d_in[17];
  const float* final_W = (const float*)d_in[18];
  const float* final_b = (const float*)d_in[19];
  float* out = (float*)d_out;

  const int N = in_sizes[2];      // 10000
  const int E = in_sizes[1] / 2;  // 80000
  const int A = E + N;

  size_t off_b = 0;
  auto alloc = [&](size_t bytes) -> void* {
    void* p = (char*)d_ws + off_b;
    off_b += (bytes + 255) & ~(size_t)255;
    return p;
  };
  unsigned short* xbf1 = (unsigned short*)alloc((size_t)N * FDIM * 2);
  unsigned short* xbf2 = (unsigned short*)alloc((size_t)N * FDIM * 2);
  unsigned short* hbf1 = (unsigned short*)alloc((size_t)N * FDIM * 2);
  unsigned short* hbf2 = (unsigned short*)alloc((size_t)N * FDIM * 2);
  unsigned short* Wt1 = (unsigned short*)alloc((size_t)FDIM * FDIM * 2);
  unsigned short* Wt2 = (unsigned short*)alloc((size_t)FDIM * FDIM * 2);
  int* deg1 = (int*)alloc(N * 4);
  int* deg2 = (int*)alloc(N * 4);
  int* cnt1 = (int*)alloc(NGRAPH * 4);
  int* cnt2 = (int*)alloc(NGRAPH * 4);
  int* gstart1 = (int*)alloc(NGRAPH * 4);
  int* gstart2 = (int*)alloc(NGRAPH * 4);
  int* off1 = (int*)alloc((N + 1) * 4);
  int* off2 = (int*)alloc((N + 1) * 4);
  int* cur1 = (int*)alloc(N * 4);
  int* cur2 = (int*)alloc(N * 4);
  float* dinv1 = (float*)alloc(N * 4);
  float* dinv2 = (float*)alloc(N * 4);
  int* adjsrc1 = (int*)alloc((size_t)A * 4);
  int* adjsrc2 = (int*)alloc((size_t)A * 4);
  float* adjw1 = (float*)alloc((size_t)A * 4);
  float* adjw2 = (float*)alloc((size_t)A * 4);
  float* pool4_1 = (float*)alloc((size_t)QN * NGRAPH * FDIM * 4);
  float* pool4_2 = (float*)alloc((size_t)QN * NGRAPH * FDIM * 4);

  const int T = 256;
  int gE = (E + T - 1) / T;                 // 313
  int n8 = N * FDIM / 8;
  int nxb = (n8 + T - 1) / T;               // 5000
  int mt = (N + 127) / 128;                 // 79
  dim3 gPrepCast(gE + nxb + 256, 2);
  dim3 gFillGemm(FILLB + mt * 8, 2);        // 320 + 632 (both mult-of-8 ranges)
  dim3 gAgg(FCH * NGRAPH * QN, 2);

  hipMemsetAsync(deg1, 0, (size_t)N * 4, stream);
  hipMemsetAsync(deg2, 0, (size_t)N * 4, stream);
  k_prep_cast<<<gPrepCast, T, 0, stream>>>(ei1, ei2, deg1, deg2,
                                           (const float4*)x1, (const float4*)x2,
                                           conv1_W, conv2_W,
                                           (u16x8*)xbf1, (u16x8*)xbf2, Wt1, Wt2,
                                           E, n8, gE, nxb);
  k_scan<<<3, SCAN_T, 0, stream>>>(deg1, deg2, off1, off2, cur1, cur2, dinv1, dinv2,
                                   batch1, batch2, cnt1, gstart1, cnt2, gstart2, N);
  k_fill_gemm<<<gFillGemm, T, 0, stream>>>(ei1, ei2, cur1, cur2, dinv1, dinv2,
                                           adjsrc1, adjsrc2, adjw1, adjw2,
                                           xbf1, xbf2, Wt1, Wt2, hbf1, hbf2,
                                           E, N, N);
  k_aggpool<<<gAgg, T, 0, stream>>>(hbf1, hbf2, off1, off2, adjsrc1, adjsrc2,
                                    adjw1, adjw2, conv1_b, conv2_b,
                                    cnt1, cnt2, gstart1, gstart2, pool4_1, pool4_2);
  k_fc_final<<<NGRAPH, T, 0, stream>>>(pool4_1, pool4_2, fc1_W, fc2_W, fc1_b, fc2_b,
                                       final_W, final_b, out);
}